// Round 12
// baseline (160.780 us; speedup 1.0000x reference)
//
#include <hip/hip_runtime.h>

#define B_    1024
#define T_    2048
#define SEAS_ 24
#define C_    6
#define W_    1977   // T - OS - IS + 1
#define SFW_  2096   // seas_full width
#define CH_   120    // chunk length (multiple of 24)
#define NCH_  17     // chunks c=0..15: 120 steps; c=16: 127 steps

typedef float vf2 __attribute__((ext_vector_type(2)));

__device__ __forceinline__ float frcp(float x) { return __builtin_amdgcn_rcpf(x); }
__device__ __forceinline__ float getc(const float4& v, int c) {
    return c == 0 ? v.x : c == 1 ? v.y : c == 2 ? v.z : v.w;   // c is compile-time
}

// One 24-step block: steps t = 24k+1 .. 24k+24. cur6 = quads 6k..6k+5 (t=24k..24k+23),
// nxt0 = quad 6k+6 (t=24k+24..). Element e = j+1; e==24 comes from nxt0.
// ILP-exposed; same arithmetic as the monolithic scan (bit-identical).
template <bool STORE>
__device__ __forceinline__ void es_block24(
    const float4* __restrict__ cur6, const float4 nxt0, float* __restrict__ s,
    float lev_a, float oma, float seas_b, float omb, float& lev,
    float* __restrict__ levp, float* __restrict__ nsp)
{
    float ar[24], lv[24];
    #pragma unroll
    for (int j = 0; j < 24; ++j) {
        const int e = j + 1, pos = (j + 1 < 24) ? (j + 1) : 0;
        float xi = (e < 24) ? getc(cur6[e >> 2], e & 3) : getc(nxt0, 0);
        ar[j] = lev_a * (xi * frcp(s[pos]));
    }
    #pragma unroll
    for (int j = 0; j < 24; ++j) {                   // serial lev chain
        lev = __builtin_fmaf(oma, lev, ar[j]);
        lv[j] = lev;
    }
    #pragma unroll
    for (int j = 0; j < 24; ++j) {                   // independent seasonal updates
        const int e = j + 1, pos = (j + 1 < 24) ? (j + 1) : 0;
        float xi = (e < 24) ? getc(cur6[e >> 2], e & 3) : getc(nxt0, 0);
        float ns = __builtin_fmaf(omb, s[pos], seas_b * (xi * frcp(lv[j])));
        s[pos] = ns;
        if (STORE) {
            levp[(size_t)j * B_] = lv[j];
            nsp[(size_t)j * B_]  = ns;
        }
    }
}

// ---------------- quad-transpose: x[b][t] -> xq[t/4][b] = float4(x[b][4q..4q+3]) -------
// Read coalesced along t; write coalesced along b (16B/lane). LDS 32x33 tile.
__global__ __launch_bounds__(256) void transposeXq_kernel(
    const float* __restrict__ x, float4* __restrict__ xq)
{
    __shared__ float tile[32][33];
    int bb = blockIdx.x * 32;                        // b tile
    int bt = blockIdx.y * 32;                        // t tile (8 quads)
    int tx = threadIdx.x, ty = threadIdx.y;          // (32, 8)
    #pragma unroll
    for (int r = 0; r < 32; r += 8)
        tile[ty + r][tx] = x[(size_t)(bb + ty + r) * T_ + bt + tx];
    __syncthreads();
    float4 v;
    v.x = tile[tx][4 * ty + 0];
    v.y = tile[tx][4 * ty + 1];
    v.z = tile[tx][4 * ty + 2];
    v.w = tile[tx][4 * ty + 3];
    xq[(size_t)(bt / 4 + ty) * B_ + bb + tx] = v;
}

// ---------------- Phase 1: state-only sequential scan, coalesced quad loads ------------
// __launch_bounds__(64,1): max VGPR budget so ping-pong buffers stay resident.
// Runs t = 1..1920; saves (s[0..23], lev) after t = 120c into state[c-1][slot][b].
__global__ __launch_bounds__(64, 1) void scan_phase1(
    const float4* __restrict__ xq, const float* __restrict__ lev_sms,
    const float* __restrict__ seas_sms, const float* __restrict__ seasonalities,
    const int* __restrict__ idxs, float* __restrict__ state)
{
    int b = blockIdx.x * 64 + threadIdx.x;

    int id = idxs[b];
    float lev_a  = 1.0f / (1.0f + __expf(-lev_sms[id]));
    float seas_b = 1.0f / (1.0f + __expf(-seas_sms[id]));
    float oma = 1.0f - lev_a, omb = 1.0f - seas_b;

    float s[SEAS_];
    #pragma unroll
    for (int j = 0; j < SEAS_; ++j) s[j] = __expf(seasonalities[id * SEAS_ + j]);

    float4 A[6], Bv[6];
    #pragma unroll
    for (int q = 0; q < 6; ++q) A[q]  = xq[(size_t)q * B_ + b];        // block 0
    #pragma unroll
    for (int q = 0; q < 6; ++q) Bv[q] = xq[(size_t)(6 + q) * B_ + b];  // block 1

    float lev = getc(A[0], 0) * frcp(s[0]);              // lev0

    for (int k = 0; k < 80; k += 2) {
        es_block24<false>(A, Bv[0], s, lev_a, oma, seas_b, omb, lev, nullptr, nullptr);
        if (((k + 1) % 5) == 0) {                        // boundary t = 24(k+1)
            int c = (k + 1) / 5 - 1;
            float* st = state + (size_t)c * 25 * B_ + b;
            #pragma unroll
            for (int j = 0; j < SEAS_; ++j) st[(size_t)j * B_] = s[j];
            st[(size_t)24 * B_] = lev;
        }
        #pragma unroll
        for (int q = 0; q < 6; ++q)                      // refill A <- block k+2 (q<=485)
            A[q] = xq[(size_t)(6 * (k + 2) + q) * B_ + b];
        es_block24<false>(Bv, A[0], s, lev_a, oma, seas_b, omb, lev, nullptr, nullptr);
        if (((k + 2) % 5) == 0) {                        // boundary t = 24(k+2)
            int c = (k + 2) / 5 - 1;
            float* st = state + (size_t)c * 25 * B_ + b;
            #pragma unroll
            for (int j = 0; j < SEAS_; ++j) st[(size_t)j * B_] = s[j];
            st[(size_t)24 * B_] = lev;
        }
        #pragma unroll
        for (int q = 0; q < 6; ++q)                      // refill B <- block k+3 (q<=491)
            Bv[q] = xq[(size_t)(6 * (k + 3) + q) * B_ + b];
    }
}

// ---------------- Phase 2: 17 exact chunks in parallel, heavy stores -------------------
// Chunk c: t in [120c+1, min(120(c+1), 2047)] (c=16 adds the 7-step tail to t=2047).
__global__ __launch_bounds__(64, 1) void scan_phase2(
    const float4* __restrict__ xq, const float* __restrict__ lev_sms,
    const float* __restrict__ seas_sms, const float* __restrict__ seasonalities,
    const int* __restrict__ idxs, const float* __restrict__ state,
    float* __restrict__ levT, float* __restrict__ nsT)
{
    int b = blockIdx.x * 64 + threadIdx.x;
    int c = blockIdx.y;

    int id = idxs[b];
    float lev_a  = 1.0f / (1.0f + __expf(-lev_sms[id]));
    float seas_b = 1.0f / (1.0f + __expf(-seas_sms[id]));
    float oma = 1.0f - lev_a, omb = 1.0f - seas_b;

    float s[SEAS_];
    float lev;
    if (c == 0) {
        #pragma unroll
        for (int j = 0; j < SEAS_; ++j) s[j] = __expf(seasonalities[id * SEAS_ + j]);
        lev = getc(xq[b], 0) * frcp(s[0]);               // lev0 (same ops as phase 1)
        levT[b] = lev;                                   // row 0
    } else {
        const float* st = state + (size_t)(c - 1) * 25 * B_ + b;
        #pragma unroll
        for (int j = 0; j < SEAS_; ++j) s[j] = st[(size_t)j * B_];
        lev = st[(size_t)24 * B_];
    }

    const int qb = 30 * c;                               // first quad (t = 120c)
    float* levp = levT + (size_t)(120 * c + 1) * B_ + b;
    float* nsp  = nsT  + (size_t)(120 * c) * B_ + b;

    float4 xv[6];
    #pragma unroll
    for (int kb = 0; kb < 5; ++kb) {                     // 5 blocks of 24 steps
        #pragma unroll
        for (int q = 0; q < 6; ++q) xv[q] = xq[(size_t)(qb + 6 * kb + q) * B_ + b];
        float4 nxt = xq[(size_t)(qb + 6 * kb + 6) * B_ + b];   // <= quad 510
        es_block24<true>(xv, nxt, s, lev_a, oma, seas_b, omb, lev, levp, nsp);
        levp += (size_t)24 * B_;
        nsp  += (size_t)24 * B_;
    }
    if (c == NCH_ - 1) {                                 // tail t = 2041..2047
        float4 tA = xq[(size_t)510 * B_ + b];            // t = 2040..2043
        float4 tB = xq[(size_t)511 * B_ + b];            // t = 2044..2047
        #pragma unroll
        for (int j = 0; j < 7; ++j) {
            const int pos = j + 1;
            float xi    = (j < 3) ? getc(tA, j + 1) : getc(tB, j - 3);
            float ratio = xi * frcp(s[pos]);
            float nl    = __builtin_fmaf(oma, lev, lev_a * ratio);
            float ns    = __builtin_fmaf(omb, s[pos], seas_b * (xi * frcp(nl)));
            s[pos] = ns;
            lev = nl;
            levp[0] = nl;  levp += B_;
            nsp[0]  = ns;  nsp  += B_;
        }
    }
}

// ---------------- transpose levT[t][b] -> out_levs[b][t] ----------------
__global__ __launch_bounds__(256) void transposeL_kernel(
    const float* __restrict__ levT, float* __restrict__ out)
{
    __shared__ float tile[32][33];
    int bt = blockIdx.y * 32;
    int bb = blockIdx.x * 32;
    int tx = threadIdx.x, ty = threadIdx.y;          // (32, 8)
    #pragma unroll
    for (int r = 0; r < 32; r += 8)
        tile[ty + r][tx] = levT[(size_t)(bt + ty + r) * B_ + bb + tx];
    __syncthreads();
    #pragma unroll
    for (int r = 0; r < 32; r += 8)
        out[(size_t)(bb + ty + r) * T_ + bt + tx] = tile[tx][ty + r];
}

// ---------------- transpose nsT -> out_seas[b][u], u in [0, 2096) ----------------
// u<25: head = exp(init_seas[idxs[b]][u<24?u:0]); u in [25,2072): row u-25;
// u in [2072,2096): row u-49 (seasonal tail repeat).
__global__ __launch_bounds__(256) void transposeS_kernel(
    const float* __restrict__ nsT, const float* __restrict__ seasonalities,
    const int* __restrict__ idxs, float* __restrict__ out_seas)
{
    __shared__ float tile[32][33];
    int bu = blockIdx.y * 32;
    int bb = blockIdx.x * 32;
    int tx = threadIdx.x, ty = threadIdx.y;
    int id = idxs[bb + tx];
    #pragma unroll
    for (int r = 0; r < 32; r += 8) {
        int u = bu + ty + r;
        if (u < 25) {
            tile[ty + r][tx] = __expf(seasonalities[id * SEAS_ + (u < 24 ? u : 0)]);
        } else if (u < SFW_) {
            int rr = u - 25 - (u >= 2072 ? 24 : 0);
            tile[ty + r][tx] = nsT[(size_t)rr * B_ + bb + tx];
        }
    }
    __syncthreads();
    #pragma unroll
    for (int r = 0; r < 32; r += 8) {
        int u = bu + tx;
        if (u < SFW_)
            out_seas[(size_t)(bb + ty + r) * SFW_ + u] = tile[tx][ty + r];
    }
}

// ---------------- window materialization (243 MB, write-bound) ----------------
__global__ __launch_bounds__(256) void win_kernel(
    const float* __restrict__ x, const float* __restrict__ levs,
    const float* __restrict__ seasF, const float* __restrict__ info_cat,
    vf2* __restrict__ out)
{
    int w  = blockIdx.y;
    int e2 = blockIdx.x * 256 + threadIdx.x;         // 0..15359 == B*15
    int b  = e2 / 15;
    int j  = e2 - b * 15;
    vf2 v;
    if (j < 12) {
        float inv = frcp(levs[b * T_ + w + 23]);
        int t = w + 2 * j;
        float sa = seasF[b * SFW_ + t];
        float sb = seasF[b * SFW_ + t + 1];
        v.x = x[b * T_ + t]     * frcp(sa) * inv;
        v.y = x[b * T_ + t + 1] * frcp(sb) * inv;
    } else {
        int c = 2 * (j - 12);
        v.x = info_cat[b * C_ + c];
        v.y = info_cat[b * C_ + c + 1];
    }
    __builtin_nontemporal_store(v, &out[(size_t)w * 15360 + e2]);
}

// ---------------- msld: mean_b (logL[i+2] - 2 logL[i+1] + logL[i])^2 ----------------
__global__ __launch_bounds__(256) void msld_kernel(
    const float* __restrict__ levT, float* __restrict__ out)
{
    int i = blockIdx.x;                              // 0..2045
    const float* r0 = levT + (size_t)i * B_;
    float ssum = 0.0f;
    #pragma unroll
    for (int r = 0; r < 4; ++r) {
        int b = threadIdx.x + 256 * r;
        float l0 = __logf(r0[b]);
        float l1 = __logf(r0[b + B_]);
        float l2 = __logf(r0[b + 2 * B_]);
        float d  = l2 - 2.0f * l1 + l0;
        ssum = __builtin_fmaf(d, d, ssum);
    }
    #pragma unroll
    for (int off = 32; off > 0; off >>= 1) ssum += __shfl_down(ssum, off);
    __shared__ float partial[4];
    int wid = threadIdx.x >> 6;
    if ((threadIdx.x & 63) == 0) partial[wid] = ssum;
    __syncthreads();
    if (threadIdx.x == 0)
        out[i] = (partial[0] + partial[1] + partial[2] + partial[3]) * (1.0f / 1024.0f);
}

extern "C" void kernel_launch(void* const* d_in, const int* in_sizes, int n_in,
                              void* d_out, int out_size, void* d_ws, size_t ws_size,
                              hipStream_t stream)
{
    const float* train    = (const float*)d_in[0];
    const float* info_cat = (const float*)d_in[3];
    const float* lev_sms  = (const float*)d_in[4];
    const float* seas_sms = (const float*)d_in[5];
    const float* seasonal = (const float*)d_in[6];
    const int*   idxs     = (const int*)d_in[7];

    float* out      = (float*)d_out;
    float* out_ib   = out;                               // W*B*30
    float* out_levs = out + (size_t)W_ * B_ * 30;        // B*2048
    float* out_seas = out_levs + (size_t)B_ * T_;        // B*2096
    float* out_msld = out_seas + (size_t)B_ * SFW_;      // 2046

    float* ws   = (float*)d_ws;
    float* levT = ws;                                    // 2048*1024 floats
    float* nsT  = ws + (size_t)T_ * B_;                  // 2047*1024 floats

    // Scratch parked in out_ib's head: state (16*25*1024 floats), then xq (8.4 MB,
    // 16B-aligned at +2MB). Both consumed before win_kernel overwrites (stream-ordered).
    float*  state = out_ib;                              // 409,600 floats
    float4* xq    = (float4*)(out_ib + 512 * 1024);      // 512 rows x 1024 float4

    transposeXq_kernel<<<dim3(B_ / 32, T_ / 32), dim3(32, 8), 0, stream>>>(train, xq);

    scan_phase1<<<B_ / 64, 64, 0, stream>>>(xq, lev_sms, seas_sms, seasonal, idxs,
                                            state);

    scan_phase2<<<dim3(B_ / 64, NCH_), 64, 0, stream>>>(xq, lev_sms, seas_sms,
                                                        seasonal, idxs, state, levT, nsT);

    msld_kernel<<<2046, 256, 0, stream>>>(levT, out_msld);

    dim3 tb(32, 8);
    transposeL_kernel<<<dim3(B_ / 32, T_ / 32), tb, 0, stream>>>(levT, out_levs);
    transposeS_kernel<<<dim3(B_ / 32, (SFW_ + 31) / 32), tb, 0, stream>>>(
        nsT, seasonal, idxs, out_seas);

    dim3 g2(60, W_);
    win_kernel<<<g2, 256, 0, stream>>>(train, out_levs, out_seas, info_cat, (vf2*)out_ib);
}

// Round 13
// 129.846 us; speedup vs baseline: 1.2382x; 1.2382x over previous
//
#include <hip/hip_runtime.h>

#define B_    1024
#define T_    2048
#define SEAS_ 24
#define C_    6
#define W_    1977   // T - OS - IS + 1
#define SFW_  2096   // seas_full width
#define CH_   120    // chunk length (multiple of 24)
#define NCH_  17     // chunks c=0..15: 120 steps; c=16: 127 steps

typedef float vf2 __attribute__((ext_vector_type(2)));

__device__ __forceinline__ float frcp(float x) { return __builtin_amdgcn_rcpf(x); }
__device__ __forceinline__ float getc(const float4& v, int c) {
    return c == 0 ? v.x : c == 1 ? v.y : c == 2 ? v.z : v.w;   // c is compile-time
}
__device__ __forceinline__ float readlane_f(float v, int l) {  // l compile-time
    return __int_as_float(__builtin_amdgcn_readlane(__float_as_int(v), l));
}

// ---------------- Phase 1: slot-parallel exact scan — ONE WAVE PER SERIES --------------
// Lane j owns step-slot j of every 24-block (slot (j+1)%24): its s value lives in a
// register permanently. Per block: lane-parallel ar = lev_a*(x*rcp(s_own)) (2 rcps of
// chained latency instead of 48), then the true serial lev chain via readlane(ar, j)
// broadcasts, then lane-parallel seasonal updates. Expression trees identical to
// phase2's es_block24 -> bit-exact state handoff.
// Saves (s, lev) after t = 120c into state[(c-1)*B + b][0..24], c = 1..16.
__global__ __launch_bounds__(64, 1) void scan_phase1(
    const float* __restrict__ x, const float* __restrict__ lev_sms,
    const float* __restrict__ seas_sms, const float* __restrict__ seasonalities,
    const int* __restrict__ idxs, float* __restrict__ state)
{
    int b    = blockIdx.x;                           // one series per wave
    int lane = threadIdx.x;                          // 0..63
    const float* xr = x + (size_t)b * T_;

    int id = idxs[b];
    float lev_a  = 1.0f / (1.0f + __expf(-lev_sms[id]));
    float seas_b = 1.0f / (1.0f + __expf(-seas_sms[id]));
    float oma = 1.0f - lev_a, omb = 1.0f - seas_b;

    int pos_own = (lane + 1 < 24) ? (lane + 1) : 0;  // lane 23 -> slot 0; lanes>=24 dummy
    float s_own = 1.0f;
    if (lane < 24) s_own = __expf(seasonalities[id * SEAS_ + pos_own]);

    float s0  = readlane_f(s_own, 23);               // slot 0 value (lane 23)
    float lev = xr[0] * frcp(s0);                    // lev0 (same ops as phase 2 c==0)
    float mylv = 1.0f;

    float xa = xr[1 + lane];                         // block 0: lane j -> x[t0 + j]
    float xb = xr[1 + 24 + lane];                    // block 1

    for (int k = 0; k < 80; k += 2) {
        // ---- block k (even): uses xa ----
        {
            float ar = lev_a * (xa * frcp(s_own));
            #pragma unroll
            for (int j = 0; j < 24; ++j) {
                float arj = readlane_f(ar, j);
                lev = __builtin_fmaf(oma, lev, arj);
                if (lane == j) mylv = lev;           // snapshot lv at own step
            }
            float ns = __builtin_fmaf(omb, s_own, seas_b * (xa * frcp(mylv)));
            if (lane < 24) s_own = ns;
        }
        xa = xr[1 + (k + 2) * 24 + lane];            // refill (always in-bounds: <=2008)
        if (((k + 1) % 5) == 0) {                    // boundary t = 24(k+1) = 120c
            int c = (k + 1) / 5 - 1;
            float* st = state + ((size_t)c * B_ + b) * 25;
            if (lane < 24) st[pos_own] = s_own;
            if (lane == 24) st[24] = lev;
        }
        // ---- block k+1 (odd): uses xb ----
        {
            float ar = lev_a * (xb * frcp(s_own));
            #pragma unroll
            for (int j = 0; j < 24; ++j) {
                float arj = readlane_f(ar, j);
                lev = __builtin_fmaf(oma, lev, arj);
                if (lane == j) mylv = lev;
            }
            float ns = __builtin_fmaf(omb, s_own, seas_b * (xb * frcp(mylv)));
            if (lane < 24) s_own = ns;
        }
        xb = xr[1 + (k + 3) * 24 + lane];            // refill (always in-bounds)
        if (((k + 2) % 5) == 0) {                    // boundary t = 24(k+2)
            int c = (k + 2) / 5 - 1;
            float* st = state + ((size_t)c * B_ + b) * 25;
            if (lane < 24) st[pos_own] = s_own;
            if (lane == 24) st[24] = lev;
        }
    }
}

// One 24-step block (steps t = 24k+1 .. 24k+24; xv = x[24k .. 24k+27], element e = j+1).
// ILP-exposed; same arithmetic as the monolithic scan (bit-identical).
template <bool STORE>
__device__ __forceinline__ void es_block24(
    const float4* __restrict__ xv, float* __restrict__ s,
    float lev_a, float oma, float seas_b, float omb, float& lev,
    float* __restrict__ levp, float* __restrict__ nsp)
{
    float ar[24], lv[24];
    #pragma unroll
    for (int j = 0; j < 24; ++j) {
        const int e = j + 1, pos = (j + 1 < 24) ? (j + 1) : 0;
        ar[j] = lev_a * (getc(xv[e >> 2], e & 3) * frcp(s[pos]));
    }
    #pragma unroll
    for (int j = 0; j < 24; ++j) {                   // serial lev chain
        lev = __builtin_fmaf(oma, lev, ar[j]);
        lv[j] = lev;
    }
    #pragma unroll
    for (int j = 0; j < 24; ++j) {                   // independent seasonal updates
        const int e = j + 1, pos = (j + 1 < 24) ? (j + 1) : 0;
        float xi = getc(xv[e >> 2], e & 3);
        float ns = __builtin_fmaf(omb, s[pos], seas_b * (xi * frcp(lv[j])));
        s[pos] = ns;
        if (STORE) {
            levp[(size_t)j * B_] = lv[j];
            nsp[(size_t)j * B_]  = ns;
        }
    }
}

// ---------------- Phase 2: 17 exact chunks in parallel, coalesced heavy stores ---------
// Chunk c: t in [120c+1, min(120(c+1), 2047)] (c=16 adds the 7-step tail to t=2047).
__global__ __launch_bounds__(64, 1) void scan_phase2(
    const float* __restrict__ x, const float* __restrict__ lev_sms,
    const float* __restrict__ seas_sms, const float* __restrict__ seasonalities,
    const int* __restrict__ idxs, const float* __restrict__ state,
    float* __restrict__ levT, float* __restrict__ nsT)
{
    int b = blockIdx.x * 64 + threadIdx.x;
    int c = blockIdx.y;
    const float4* xr4 = (const float4*)(x + (size_t)b * T_);

    int id = idxs[b];
    float lev_a  = 1.0f / (1.0f + __expf(-lev_sms[id]));
    float seas_b = 1.0f / (1.0f + __expf(-seas_sms[id]));
    float oma = 1.0f - lev_a, omb = 1.0f - seas_b;

    float s[SEAS_];
    float lev;
    if (c == 0) {
        #pragma unroll
        for (int j = 0; j < SEAS_; ++j) s[j] = __expf(seasonalities[id * SEAS_ + j]);
        lev = getc(xr4[0], 0) * frcp(s[0]);              // lev0 (same ops as phase 1)
        levT[b] = lev;                                   // row 0
    } else {
        const float* st = state + ((size_t)(c - 1) * B_ + b) * 25;
        #pragma unroll
        for (int j = 0; j < SEAS_; ++j) s[j] = st[j];
        lev = st[24];
    }

    float4 xv[7], xn[7];
    const float4* base0 = xr4 + 30 * c;                  // t = 120c ..
    #pragma unroll
    for (int q = 0; q < 7; ++q) xv[q] = base0[q];

    float* levp = levT + (size_t)(120 * c + 1) * B_ + b;
    float* nsp  = nsT  + (size_t)(120 * c) * B_ + b;

    #pragma unroll
    for (int kb = 0; kb < 5; ++kb) {                     // 5 blocks of 24 steps
        const float4* nb = xr4 + 30 * c + 6 * (kb + 1);
        if (c == NCH_ - 1 && kb == 4) {                  // next base 510: only 2 in-bounds
            xn[0] = nb[0]; xn[1] = nb[1];
        } else {
            #pragma unroll
            for (int q = 0; q < 7; ++q) xn[q] = nb[q];
        }
        es_block24<true>(xv, s, lev_a, oma, seas_b, omb, lev, levp, nsp);
        levp += (size_t)24 * B_;
        nsp  += (size_t)24 * B_;
        #pragma unroll
        for (int q = 0; q < 7; ++q) xv[q] = xn[q];
    }
    if (c == NCH_ - 1) {                                 // tail t = 2041..2047
        #pragma unroll
        for (int j = 0; j < 7; ++j) {
            const int e = j + 1, pos = j + 1;
            float xi    = getc(xv[e >> 2], e & 3);
            float ratio = xi * frcp(s[pos]);
            float nl    = __builtin_fmaf(oma, lev, lev_a * ratio);
            float ns    = __builtin_fmaf(omb, s[pos], seas_b * (xi * frcp(nl)));
            s[pos] = ns;
            lev = nl;
            levp[0] = nl;  levp += B_;
            nsp[0]  = ns;  nsp  += B_;
        }
    }
}

// ---------------- transpose levT[t][b] -> out_levs[b][t] ----------------
__global__ __launch_bounds__(256) void transposeL_kernel(
    const float* __restrict__ levT, float* __restrict__ out)
{
    __shared__ float tile[32][33];
    int bt = blockIdx.y * 32;
    int bb = blockIdx.x * 32;
    int tx = threadIdx.x, ty = threadIdx.y;          // (32, 8)
    #pragma unroll
    for (int r = 0; r < 32; r += 8)
        tile[ty + r][tx] = levT[(size_t)(bt + ty + r) * B_ + bb + tx];
    __syncthreads();
    #pragma unroll
    for (int r = 0; r < 32; r += 8)
        out[(size_t)(bb + ty + r) * T_ + bt + tx] = tile[tx][ty + r];
}

// ---------------- transpose nsT -> out_seas[b][u], u in [0, 2096) ----------------
// u<25: head = exp(init_seas[idxs[b]][u<24?u:0]); u in [25,2072): row u-25;
// u in [2072,2096): row u-49 (seasonal tail repeat).
__global__ __launch_bounds__(256) void transposeS_kernel(
    const float* __restrict__ nsT, const float* __restrict__ seasonalities,
    const int* __restrict__ idxs, float* __restrict__ out_seas)
{
    __shared__ float tile[32][33];
    int bu = blockIdx.y * 32;
    int bb = blockIdx.x * 32;
    int tx = threadIdx.x, ty = threadIdx.y;
    int id = idxs[bb + tx];
    #pragma unroll
    for (int r = 0; r < 32; r += 8) {
        int u = bu + ty + r;
        if (u < 25) {
            tile[ty + r][tx] = __expf(seasonalities[id * SEAS_ + (u < 24 ? u : 0)]);
        } else if (u < SFW_) {
            int rr = u - 25 - (u >= 2072 ? 24 : 0);
            tile[ty + r][tx] = nsT[(size_t)rr * B_ + bb + tx];
        }
    }
    __syncthreads();
    #pragma unroll
    for (int r = 0; r < 32; r += 8) {
        int u = bu + tx;
        if (u < SFW_)
            out_seas[(size_t)(bb + ty + r) * SFW_ + u] = tile[tx][ty + r];
    }
}

// ---------------- window materialization (243 MB, write-bound) ----------------
__global__ __launch_bounds__(256) void win_kernel(
    const float* __restrict__ x, const float* __restrict__ levs,
    const float* __restrict__ seasF, const float* __restrict__ info_cat,
    vf2* __restrict__ out)
{
    int w  = blockIdx.y;
    int e2 = blockIdx.x * 256 + threadIdx.x;         // 0..15359 == B*15
    int b  = e2 / 15;
    int j  = e2 - b * 15;
    vf2 v;
    if (j < 12) {
        float inv = frcp(levs[b * T_ + w + 23]);
        int t = w + 2 * j;
        float sa = seasF[b * SFW_ + t];
        float sb = seasF[b * SFW_ + t + 1];
        v.x = x[b * T_ + t]     * frcp(sa) * inv;
        v.y = x[b * T_ + t + 1] * frcp(sb) * inv;
    } else {
        int c = 2 * (j - 12);
        v.x = info_cat[b * C_ + c];
        v.y = info_cat[b * C_ + c + 1];
    }
    __builtin_nontemporal_store(v, &out[(size_t)w * 15360 + e2]);
}

// ---------------- msld: mean_b (logL[i+2] - 2 logL[i+1] + logL[i])^2 ----------------
__global__ __launch_bounds__(256) void msld_kernel(
    const float* __restrict__ levT, float* __restrict__ out)
{
    int i = blockIdx.x;                              // 0..2045
    const float* r0 = levT + (size_t)i * B_;
    float ssum = 0.0f;
    #pragma unroll
    for (int r = 0; r < 4; ++r) {
        int b = threadIdx.x + 256 * r;
        float l0 = __logf(r0[b]);
        float l1 = __logf(r0[b + B_]);
        float l2 = __logf(r0[b + 2 * B_]);
        float d  = l2 - 2.0f * l1 + l0;
        ssum = __builtin_fmaf(d, d, ssum);
    }
    #pragma unroll
    for (int off = 32; off > 0; off >>= 1) ssum += __shfl_down(ssum, off);
    __shared__ float partial[4];
    int wid = threadIdx.x >> 6;
    if ((threadIdx.x & 63) == 0) partial[wid] = ssum;
    __syncthreads();
    if (threadIdx.x == 0)
        out[i] = (partial[0] + partial[1] + partial[2] + partial[3]) * (1.0f / 1024.0f);
}

extern "C" void kernel_launch(void* const* d_in, const int* in_sizes, int n_in,
                              void* d_out, int out_size, void* d_ws, size_t ws_size,
                              hipStream_t stream)
{
    const float* train    = (const float*)d_in[0];
    const float* info_cat = (const float*)d_in[3];
    const float* lev_sms  = (const float*)d_in[4];
    const float* seas_sms = (const float*)d_in[5];
    const float* seasonal = (const float*)d_in[6];
    const int*   idxs     = (const int*)d_in[7];

    float* out      = (float*)d_out;
    float* out_ib   = out;                               // W*B*30
    float* out_levs = out + (size_t)W_ * B_ * 30;        // B*2048
    float* out_seas = out_levs + (size_t)B_ * T_;        // B*2096
    float* out_msld = out_seas + (size_t)B_ * SFW_;      // 2046

    float* ws   = (float*)d_ws;
    float* levT = ws;                                    // 2048*1024 floats
    float* nsT  = ws + (size_t)T_ * B_;                  // 2047*1024 floats

    // Exact boundary states live in the head of out_ib: written by phase1, read by
    // phase2, later overwritten by win_kernel (stream-ordered, race-free).
    float* state = out_ib;                               // 16*1024*25 floats (1.6 MB)

    scan_phase1<<<B_, 64, 0, stream>>>(train, lev_sms, seas_sms, seasonal, idxs, state);

    scan_phase2<<<dim3(B_ / 64, NCH_), 64, 0, stream>>>(train, lev_sms, seas_sms,
                                                        seasonal, idxs, state, levT, nsT);

    msld_kernel<<<2046, 256, 0, stream>>>(levT, out_msld);

    dim3 tb(32, 8);
    transposeL_kernel<<<dim3(B_ / 32, T_ / 32), tb, 0, stream>>>(levT, out_levs);
    transposeS_kernel<<<dim3(B_ / 32, (SFW_ + 31) / 32), tb, 0, stream>>>(
        nsT, seasonal, idxs, out_seas);

    dim3 g2(60, W_);
    win_kernel<<<g2, 256, 0, stream>>>(train, out_levs, out_seas, info_cat, (vf2*)out_ib);
}

// Round 14
// 128.801 us; speedup vs baseline: 1.2483x; 1.0081x over previous
//
#include <hip/hip_runtime.h>

#define B_    1024
#define T_    2048
#define SEAS_ 24
#define C_    6
#define W_    1977   // T - OS - IS + 1
#define SFW_  2096   // seas_full width
#define CH_   120    // chunk length (multiple of 24)
#define NCH_  17     // chunks c=0..15: 120 steps; c=16: 127 steps

typedef float vf2 __attribute__((ext_vector_type(2)));

__device__ __forceinline__ float frcp(float x) { return __builtin_amdgcn_rcpf(x); }
__device__ __forceinline__ float getc(const float4& v, int c) {
    return c == 0 ? v.x : c == 1 ? v.y : c == 2 ? v.z : v.w;   // c is compile-time
}
__device__ __forceinline__ float readlane_f(float v, int l) {  // l compile-time
    return __int_as_float(__builtin_amdgcn_readlane(__float_as_int(v), l));
}

// One slot-parallel 24-step block: lane j owns slot (j+1)%24; xv = lane's x[t0+lane].
// Expression tree identical to es_block24 -> bit-exact.
__device__ __forceinline__ void slot_block(
    float xv, float& s_own, float& lev, float& mylv, int lane,
    float lev_a, float oma, float seas_b, float omb)
{
    float ar = lev_a * (xv * frcp(s_own));
    #pragma unroll
    for (int j = 0; j < 24; ++j) {
        float arj = readlane_f(ar, j);
        lev = __builtin_fmaf(oma, lev, arj);
        if (lane == j) mylv = lev;                   // snapshot lv at own step
    }
    float ns = __builtin_fmaf(omb, s_own, seas_b * (xv * frcp(mylv)));
    if (lane < 24) s_own = ns;
}

// ---------------- Phase 1: slot-parallel exact scan, depth-5 load prefetch -------------
// One wave per series. Five x registers rotate: block k's refill targets block k+5,
// giving ~4 blocks (~1000 cyc) of latency cover vs ~900 cyc HBM miss. A 5-block group
// = 120 steps = one chunk, so the state save is unconditional at group end.
__global__ __launch_bounds__(64, 1) void scan_phase1(
    const float* __restrict__ x, const float* __restrict__ lev_sms,
    const float* __restrict__ seas_sms, const float* __restrict__ seasonalities,
    const int* __restrict__ idxs, float* __restrict__ state)
{
    int b    = blockIdx.x;                           // one series per wave
    int lane = threadIdx.x;                          // 0..63
    const float* xr = x + (size_t)b * T_;

    int id = idxs[b];
    float lev_a  = 1.0f / (1.0f + __expf(-lev_sms[id]));
    float seas_b = 1.0f / (1.0f + __expf(-seas_sms[id]));
    float oma = 1.0f - lev_a, omb = 1.0f - seas_b;

    int pos_own = (lane + 1 < 24) ? (lane + 1) : 0;  // lane 23 -> slot 0; lanes>=24 dummy
    float s_own = 1.0f;
    if (lane < 24) s_own = __expf(seasonalities[id * SEAS_ + pos_own]);

    float s0  = readlane_f(s_own, 23);               // slot 0 value (lane 23)
    float lev = xr[0] * frcp(s0);                    // lev0 (same ops as phase 2 c==0)
    float mylv = 1.0f;

    float xq0 = xr[1 + lane];                        // blocks 0..4 preloaded
    float xq1 = xr[1 + 24 + lane];
    float xq2 = xr[1 + 48 + lane];
    float xq3 = xr[1 + 72 + lane];
    float xq4 = xr[1 + 96 + lane];

    for (int g = 0; g < 16; ++g) {                   // 16 groups x 5 blocks = t 1..1920
        int base = 1 + (5 * g + 5) * 24 + lane;      // refill target: block 5g+5+i
        slot_block(xq0, s_own, lev, mylv, lane, lev_a, oma, seas_b, omb);
        { int t = base;      xq0 = xr[t > 2047 ? 2047 : t]; }
        slot_block(xq1, s_own, lev, mylv, lane, lev_a, oma, seas_b, omb);
        { int t = base + 24; xq1 = xr[t > 2047 ? 2047 : t]; }
        slot_block(xq2, s_own, lev, mylv, lane, lev_a, oma, seas_b, omb);
        { int t = base + 48; xq2 = xr[t > 2047 ? 2047 : t]; }
        slot_block(xq3, s_own, lev, mylv, lane, lev_a, oma, seas_b, omb);
        { int t = base + 72; xq3 = xr[t > 2047 ? 2047 : t]; }
        slot_block(xq4, s_own, lev, mylv, lane, lev_a, oma, seas_b, omb);
        { int t = base + 96; xq4 = xr[t > 2047 ? 2047 : t]; }
        float* st = state + ((size_t)g * B_ + b) * 25;   // t = 120(g+1) done
        if (lane < 24) st[pos_own] = s_own;
        if (lane == 24) st[24] = lev;
    }
}

// One 24-step block (steps t = 24k+1 .. 24k+24; xv = x[24k .. 24k+27], element e = j+1).
// ILP-exposed; same arithmetic as the monolithic scan (bit-identical).
template <bool STORE>
__device__ __forceinline__ void es_block24(
    const float4* __restrict__ xv, float* __restrict__ s,
    float lev_a, float oma, float seas_b, float omb, float& lev,
    float* __restrict__ levp, float* __restrict__ nsp)
{
    float ar[24], lv[24];
    #pragma unroll
    for (int j = 0; j < 24; ++j) {
        const int e = j + 1, pos = (j + 1 < 24) ? (j + 1) : 0;
        ar[j] = lev_a * (getc(xv[e >> 2], e & 3) * frcp(s[pos]));
    }
    #pragma unroll
    for (int j = 0; j < 24; ++j) {                   // serial lev chain
        lev = __builtin_fmaf(oma, lev, ar[j]);
        lv[j] = lev;
    }
    #pragma unroll
    for (int j = 0; j < 24; ++j) {                   // independent seasonal updates
        const int e = j + 1, pos = (j + 1 < 24) ? (j + 1) : 0;
        float xi = getc(xv[e >> 2], e & 3);
        float ns = __builtin_fmaf(omb, s[pos], seas_b * (xi * frcp(lv[j])));
        s[pos] = ns;
        if (STORE) {
            levp[(size_t)j * B_] = lv[j];
            nsp[(size_t)j * B_]  = ns;
        }
    }
}

// ---------------- Phase 2: 17 exact chunks in parallel, coalesced heavy stores ---------
// Chunk c: t in [120c+1, min(120(c+1), 2047)] (c=16 adds the 7-step tail to t=2047).
__global__ __launch_bounds__(64, 1) void scan_phase2(
    const float* __restrict__ x, const float* __restrict__ lev_sms,
    const float* __restrict__ seas_sms, const float* __restrict__ seasonalities,
    const int* __restrict__ idxs, const float* __restrict__ state,
    float* __restrict__ levT, float* __restrict__ nsT)
{
    int b = blockIdx.x * 64 + threadIdx.x;
    int c = blockIdx.y;
    const float4* xr4 = (const float4*)(x + (size_t)b * T_);

    int id = idxs[b];
    float lev_a  = 1.0f / (1.0f + __expf(-lev_sms[id]));
    float seas_b = 1.0f / (1.0f + __expf(-seas_sms[id]));
    float oma = 1.0f - lev_a, omb = 1.0f - seas_b;

    float s[SEAS_];
    float lev;
    if (c == 0) {
        #pragma unroll
        for (int j = 0; j < SEAS_; ++j) s[j] = __expf(seasonalities[id * SEAS_ + j]);
        lev = getc(xr4[0], 0) * frcp(s[0]);              // lev0 (same ops as phase 1)
        levT[b] = lev;                                   // row 0
    } else {
        const float* st = state + ((size_t)(c - 1) * B_ + b) * 25;
        #pragma unroll
        for (int j = 0; j < SEAS_; ++j) s[j] = st[j];
        lev = st[24];
    }

    float4 xv[7], xn[7];
    const float4* base0 = xr4 + 30 * c;                  // t = 120c ..
    #pragma unroll
    for (int q = 0; q < 7; ++q) xv[q] = base0[q];

    float* levp = levT + (size_t)(120 * c + 1) * B_ + b;
    float* nsp  = nsT  + (size_t)(120 * c) * B_ + b;

    #pragma unroll
    for (int kb = 0; kb < 5; ++kb) {                     // 5 blocks of 24 steps
        const float4* nb = xr4 + 30 * c + 6 * (kb + 1);
        if (c == NCH_ - 1 && kb == 4) {                  // next base 510: only 2 in-bounds
            xn[0] = nb[0]; xn[1] = nb[1];
        } else {
            #pragma unroll
            for (int q = 0; q < 7; ++q) xn[q] = nb[q];
        }
        es_block24<true>(xv, s, lev_a, oma, seas_b, omb, lev, levp, nsp);
        levp += (size_t)24 * B_;
        nsp  += (size_t)24 * B_;
        #pragma unroll
        for (int q = 0; q < 7; ++q) xv[q] = xn[q];
    }
    if (c == NCH_ - 1) {                                 // tail t = 2041..2047
        #pragma unroll
        for (int j = 0; j < 7; ++j) {
            const int e = j + 1, pos = j + 1;
            float xi    = getc(xv[e >> 2], e & 3);
            float ratio = xi * frcp(s[pos]);
            float nl    = __builtin_fmaf(oma, lev, lev_a * ratio);
            float ns    = __builtin_fmaf(omb, s[pos], seas_b * (xi * frcp(nl)));
            s[pos] = ns;
            lev = nl;
            levp[0] = nl;  levp += B_;
            nsp[0]  = ns;  nsp  += B_;
        }
    }
}

// ---------------- transpose levT[t][b] -> out_levs[b][t] ----------------
__global__ __launch_bounds__(256) void transposeL_kernel(
    const float* __restrict__ levT, float* __restrict__ out)
{
    __shared__ float tile[32][33];
    int bt = blockIdx.y * 32;
    int bb = blockIdx.x * 32;
    int tx = threadIdx.x, ty = threadIdx.y;          // (32, 8)
    #pragma unroll
    for (int r = 0; r < 32; r += 8)
        tile[ty + r][tx] = levT[(size_t)(bt + ty + r) * B_ + bb + tx];
    __syncthreads();
    #pragma unroll
    for (int r = 0; r < 32; r += 8)
        out[(size_t)(bb + ty + r) * T_ + bt + tx] = tile[tx][ty + r];
}

// ---------------- transpose nsT -> out_seas[b][u], u in [0, 2096) ----------------
// u<25: head = exp(init_seas[idxs[b]][u<24?u:0]); u in [25,2072): row u-25;
// u in [2072,2096): row u-49 (seasonal tail repeat).
__global__ __launch_bounds__(256) void transposeS_kernel(
    const float* __restrict__ nsT, const float* __restrict__ seasonalities,
    const int* __restrict__ idxs, float* __restrict__ out_seas)
{
    __shared__ float tile[32][33];
    int bu = blockIdx.y * 32;
    int bb = blockIdx.x * 32;
    int tx = threadIdx.x, ty = threadIdx.y;
    int id = idxs[bb + tx];
    #pragma unroll
    for (int r = 0; r < 32; r += 8) {
        int u = bu + ty + r;
        if (u < 25) {
            tile[ty + r][tx] = __expf(seasonalities[id * SEAS_ + (u < 24 ? u : 0)]);
        } else if (u < SFW_) {
            int rr = u - 25 - (u >= 2072 ? 24 : 0);
            tile[ty + r][tx] = nsT[(size_t)rr * B_ + bb + tx];
        }
    }
    __syncthreads();
    #pragma unroll
    for (int r = 0; r < 32; r += 8) {
        int u = bu + tx;
        if (u < SFW_)
            out_seas[(size_t)(bb + ty + r) * SFW_ + u] = tile[tx][ty + r];
    }
}

// ---------------- window materialization (243 MB, write-bound) ----------------
__global__ __launch_bounds__(256) void win_kernel(
    const float* __restrict__ x, const float* __restrict__ levs,
    const float* __restrict__ seasF, const float* __restrict__ info_cat,
    vf2* __restrict__ out)
{
    int w  = blockIdx.y;
    int e2 = blockIdx.x * 256 + threadIdx.x;         // 0..15359 == B*15
    int b  = e2 / 15;
    int j  = e2 - b * 15;
    vf2 v;
    if (j < 12) {
        float inv = frcp(levs[b * T_ + w + 23]);
        int t = w + 2 * j;
        float sa = seasF[b * SFW_ + t];
        float sb = seasF[b * SFW_ + t + 1];
        v.x = x[b * T_ + t]     * frcp(sa) * inv;
        v.y = x[b * T_ + t + 1] * frcp(sb) * inv;
    } else {
        int c = 2 * (j - 12);
        v.x = info_cat[b * C_ + c];
        v.y = info_cat[b * C_ + c + 1];
    }
    __builtin_nontemporal_store(v, &out[(size_t)w * 15360 + e2]);
}

// ---------------- msld: mean_b (logL[i+2] - 2 logL[i+1] + logL[i])^2 ----------------
__global__ __launch_bounds__(256) void msld_kernel(
    const float* __restrict__ levT, float* __restrict__ out)
{
    int i = blockIdx.x;                              // 0..2045
    const float* r0 = levT + (size_t)i * B_;
    float ssum = 0.0f;
    #pragma unroll
    for (int r = 0; r < 4; ++r) {
        int b = threadIdx.x + 256 * r;
        float l0 = __logf(r0[b]);
        float l1 = __logf(r0[b + B_]);
        float l2 = __logf(r0[b + 2 * B_]);
        float d  = l2 - 2.0f * l1 + l0;
        ssum = __builtin_fmaf(d, d, ssum);
    }
    #pragma unroll
    for (int off = 32; off > 0; off >>= 1) ssum += __shfl_down(ssum, off);
    __shared__ float partial[4];
    int wid = threadIdx.x >> 6;
    if ((threadIdx.x & 63) == 0) partial[wid] = ssum;
    __syncthreads();
    if (threadIdx.x == 0)
        out[i] = (partial[0] + partial[1] + partial[2] + partial[3]) * (1.0f / 1024.0f);
}

extern "C" void kernel_launch(void* const* d_in, const int* in_sizes, int n_in,
                              void* d_out, int out_size, void* d_ws, size_t ws_size,
                              hipStream_t stream)
{
    const float* train    = (const float*)d_in[0];
    const float* info_cat = (const float*)d_in[3];
    const float* lev_sms  = (const float*)d_in[4];
    const float* seas_sms = (const float*)d_in[5];
    const float* seasonal = (const float*)d_in[6];
    const int*   idxs     = (const int*)d_in[7];

    float* out      = (float*)d_out;
    float* out_ib   = out;                               // W*B*30
    float* out_levs = out + (size_t)W_ * B_ * 30;        // B*2048
    float* out_seas = out_levs + (size_t)B_ * T_;        // B*2096
    float* out_msld = out_seas + (size_t)B_ * SFW_;      // 2046

    float* ws   = (float*)d_ws;
    float* levT = ws;                                    // 2048*1024 floats
    float* nsT  = ws + (size_t)T_ * B_;                  // 2047*1024 floats

    // Exact boundary states live in the head of out_ib: written by phase1, read by
    // phase2, later overwritten by win_kernel (stream-ordered, race-free).
    float* state = out_ib;                               // 16*1024*25 floats (1.6 MB)

    scan_phase1<<<B_, 64, 0, stream>>>(train, lev_sms, seas_sms, seasonal, idxs, state);

    scan_phase2<<<dim3(B_ / 64, NCH_), 64, 0, stream>>>(train, lev_sms, seas_sms,
                                                        seasonal, idxs, state, levT, nsT);

    msld_kernel<<<2046, 256, 0, stream>>>(levT, out_msld);

    dim3 tb(32, 8);
    transposeL_kernel<<<dim3(B_ / 32, T_ / 32), tb, 0, stream>>>(levT, out_levs);
    transposeS_kernel<<<dim3(B_ / 32, (SFW_ + 31) / 32), tb, 0, stream>>>(
        nsT, seasonal, idxs, out_seas);

    dim3 g2(60, W_);
    win_kernel<<<g2, 256, 0, stream>>>(train, out_levs, out_seas, info_cat, (vf2*)out_ib);
}

// Round 15
// 120.659 us; speedup vs baseline: 1.3325x; 1.0675x over previous
//
#include <hip/hip_runtime.h>

#define B_    1024
#define T_    2048
#define SEAS_ 24
#define C_    6
#define W_    1977   // T - OS - IS + 1
#define SFW_  2096   // seas_full width
#define CH_   120    // chunk length (multiple of 24)
#define NCH_  17     // chunks c=0..15: 120 steps; c=16: 127 steps

typedef float vf2 __attribute__((ext_vector_type(2)));

__device__ __forceinline__ float frcp(float x) { return __builtin_amdgcn_rcpf(x); }
__device__ __forceinline__ float getc(const float4& v, int c) {
    return c == 0 ? v.x : c == 1 ? v.y : c == 2 ? v.z : v.w;   // c is compile-time
}

// ---------------- Phase 1: shuffle-scan exact-state scan — ONE WAVE PER SERIES ---------
// Lane j owns step-slot j (seasonal slot (j+1)%24). Per 24-step block:
//   ar_j = lev_a*(x_j*rcp(s_own))                        (lane-parallel)
//   acc_j = sum_{i<=j} oma^{j-i} ar_i                    (weighted Kogge-Stone, 5 shfl_up
//                                                         + 5 unconditional FMAs; lanes
//                                                         with lane<d use weight 0)
//   lv_j  = fma(oma^{j+1}, lev_prev, acc_j)              (per-lane constant myp)
//   ns_j  = fma(omb, s_own, seas_b*(x_j*rcp(lv_j)))      (lane-parallel)
//   carry: lev_prev = shfl(lv, 23)
// No per-step conditionals/readlanes -> no exec-mask churn. Arithmetic is a contraction
// (factor ~0.38/step), so the scan's reassociation error stays at ~1e-7 relative.
__device__ __forceinline__ void scan_block(
    float xv, float& s_own, float& lev, float lev_a, float seas_b, float omb,
    float w1, float w2, float w4, float w8, float w16, float myp)
{
    float ar  = lev_a * (xv * frcp(s_own));
    float acc = ar;
    float t;
    t = __shfl_up(acc, 1);   acc = __builtin_fmaf(w1,  t, acc);
    t = __shfl_up(acc, 2);   acc = __builtin_fmaf(w2,  t, acc);
    t = __shfl_up(acc, 4);   acc = __builtin_fmaf(w4,  t, acc);
    t = __shfl_up(acc, 8);   acc = __builtin_fmaf(w8,  t, acc);
    t = __shfl_up(acc, 16);  acc = __builtin_fmaf(w16, t, acc);
    float lv = __builtin_fmaf(myp, lev, acc);        // lev after own step
    float ns = __builtin_fmaf(omb, s_own, seas_b * (xv * frcp(lv)));
    s_own = ns;                                      // lanes >= 24 carry harmless junk
    lev = __shfl(lv, 23);                            // block carry (step 23 = slot 0)
}

__global__ __launch_bounds__(64, 1) void scan_phase1(
    const float* __restrict__ x, const float* __restrict__ lev_sms,
    const float* __restrict__ seas_sms, const float* __restrict__ seasonalities,
    const int* __restrict__ idxs, float* __restrict__ state)
{
    int b    = blockIdx.x;                           // one series per wave
    int lane = threadIdx.x;                          // 0..63
    const float* xr = x + (size_t)b * T_;

    int id = idxs[b];
    float lev_a  = 1.0f / (1.0f + __expf(-lev_sms[id]));
    float seas_b = 1.0f / (1.0f + __expf(-seas_sms[id]));
    float oma = 1.0f - lev_a, omb = 1.0f - seas_b;

    // powers of oma: scan-step weights (0 below the step distance) + per-lane oma^(lane+1)
    float p1 = oma, p2 = p1 * p1, p4 = p2 * p2, p8 = p4 * p4, p16 = p8 * p8;
    float w1  = (lane >= 1)  ? p1  : 0.0f;
    float w2  = (lane >= 2)  ? p2  : 0.0f;
    float w4  = (lane >= 4)  ? p4  : 0.0f;
    float w8  = (lane >= 8)  ? p8  : 0.0f;
    float w16 = (lane >= 16) ? p16 : 0.0f;
    int lp1 = lane + 1;
    float myp = ((lp1 & 1)  ? p1  : 1.0f) * ((lp1 & 2)  ? p2  : 1.0f)
              * ((lp1 & 4)  ? p4  : 1.0f) * ((lp1 & 8)  ? p8  : 1.0f)
              * ((lp1 & 16) ? p16 : 1.0f);           // oma^(lane+1)

    int pos_own = (lane + 1 < 24) ? (lane + 1) : 0;  // lane 23 -> slot 0
    float s_own = 1.0f;
    if (lane < 24) s_own = __expf(seasonalities[id * SEAS_ + pos_own]);

    float s0  = __shfl(s_own, 23);                   // slot 0 initial value
    float lev = xr[0] * frcp(s0);                    // lev0

    float xq0 = xr[1 + lane];                        // blocks 0..4 preloaded
    float xq1 = xr[1 + 24 + lane];
    float xq2 = xr[1 + 48 + lane];
    float xq3 = xr[1 + 72 + lane];
    float xq4 = xr[1 + 96 + lane];

    for (int g = 0; g < 16; ++g) {                   // 16 groups x 5 blocks = t 1..1920
        int base = 1 + (5 * g + 5) * 24 + lane;      // refill target: block 5g+5+i
        scan_block(xq0, s_own, lev, lev_a, seas_b, omb, w1, w2, w4, w8, w16, myp);
        { int t = base;      xq0 = xr[t > 2047 ? 2047 : t]; }
        scan_block(xq1, s_own, lev, lev_a, seas_b, omb, w1, w2, w4, w8, w16, myp);
        { int t = base + 24; xq1 = xr[t > 2047 ? 2047 : t]; }
        scan_block(xq2, s_own, lev, lev_a, seas_b, omb, w1, w2, w4, w8, w16, myp);
        { int t = base + 48; xq2 = xr[t > 2047 ? 2047 : t]; }
        scan_block(xq3, s_own, lev, lev_a, seas_b, omb, w1, w2, w4, w8, w16, myp);
        { int t = base + 72; xq3 = xr[t > 2047 ? 2047 : t]; }
        scan_block(xq4, s_own, lev, lev_a, seas_b, omb, w1, w2, w4, w8, w16, myp);
        { int t = base + 96; xq4 = xr[t > 2047 ? 2047 : t]; }
        float* st = state + ((size_t)g * B_ + b) * 25;   // t = 120(g+1) done
        if (lane < 24) st[pos_own] = s_own;
        if (lane == 24) st[24] = lev;
    }
}

// One 24-step block (steps t = 24k+1 .. 24k+24; xv = x[24k .. 24k+27], element e = j+1).
// ILP-exposed sequential arithmetic (exact within each chunk).
template <bool STORE>
__device__ __forceinline__ void es_block24(
    const float4* __restrict__ xv, float* __restrict__ s,
    float lev_a, float oma, float seas_b, float omb, float& lev,
    float* __restrict__ levp, float* __restrict__ nsp)
{
    float ar[24], lv[24];
    #pragma unroll
    for (int j = 0; j < 24; ++j) {
        const int e = j + 1, pos = (j + 1 < 24) ? (j + 1) : 0;
        ar[j] = lev_a * (getc(xv[e >> 2], e & 3) * frcp(s[pos]));
    }
    #pragma unroll
    for (int j = 0; j < 24; ++j) {                   // serial lev chain
        lev = __builtin_fmaf(oma, lev, ar[j]);
        lv[j] = lev;
    }
    #pragma unroll
    for (int j = 0; j < 24; ++j) {                   // independent seasonal updates
        const int e = j + 1, pos = (j + 1 < 24) ? (j + 1) : 0;
        float xi = getc(xv[e >> 2], e & 3);
        float ns = __builtin_fmaf(omb, s[pos], seas_b * (xi * frcp(lv[j])));
        s[pos] = ns;
        if (STORE) {
            levp[(size_t)j * B_] = lv[j];
            nsp[(size_t)j * B_]  = ns;
        }
    }
}

// ---------------- Phase 2: 17 exact chunks in parallel, coalesced heavy stores ---------
// Chunk c: t in [120c+1, min(120(c+1), 2047)] (c=16 adds the 7-step tail to t=2047).
__global__ __launch_bounds__(64, 1) void scan_phase2(
    const float* __restrict__ x, const float* __restrict__ lev_sms,
    const float* __restrict__ seas_sms, const float* __restrict__ seasonalities,
    const int* __restrict__ idxs, const float* __restrict__ state,
    float* __restrict__ levT, float* __restrict__ nsT)
{
    int b = blockIdx.x * 64 + threadIdx.x;
    int c = blockIdx.y;
    const float4* xr4 = (const float4*)(x + (size_t)b * T_);

    int id = idxs[b];
    float lev_a  = 1.0f / (1.0f + __expf(-lev_sms[id]));
    float seas_b = 1.0f / (1.0f + __expf(-seas_sms[id]));
    float oma = 1.0f - lev_a, omb = 1.0f - seas_b;

    float s[SEAS_];
    float lev;
    if (c == 0) {
        #pragma unroll
        for (int j = 0; j < SEAS_; ++j) s[j] = __expf(seasonalities[id * SEAS_ + j]);
        lev = getc(xr4[0], 0) * frcp(s[0]);              // lev0
        levT[b] = lev;                                   // row 0
    } else {
        const float* st = state + ((size_t)(c - 1) * B_ + b) * 25;
        #pragma unroll
        for (int j = 0; j < SEAS_; ++j) s[j] = st[j];
        lev = st[24];
    }

    float4 xv[7], xn[7];
    const float4* base0 = xr4 + 30 * c;                  // t = 120c ..
    #pragma unroll
    for (int q = 0; q < 7; ++q) xv[q] = base0[q];

    float* levp = levT + (size_t)(120 * c + 1) * B_ + b;
    float* nsp  = nsT  + (size_t)(120 * c) * B_ + b;

    #pragma unroll
    for (int kb = 0; kb < 5; ++kb) {                     // 5 blocks of 24 steps
        const float4* nb = xr4 + 30 * c + 6 * (kb + 1);
        if (c == NCH_ - 1 && kb == 4) {                  // next base 510: only 2 in-bounds
            xn[0] = nb[0]; xn[1] = nb[1];
        } else {
            #pragma unroll
            for (int q = 0; q < 7; ++q) xn[q] = nb[q];
        }
        es_block24<true>(xv, s, lev_a, oma, seas_b, omb, lev, levp, nsp);
        levp += (size_t)24 * B_;
        nsp  += (size_t)24 * B_;
        #pragma unroll
        for (int q = 0; q < 7; ++q) xv[q] = xn[q];
    }
    if (c == NCH_ - 1) {                                 // tail t = 2041..2047
        #pragma unroll
        for (int j = 0; j < 7; ++j) {
            const int e = j + 1, pos = j + 1;
            float xi    = getc(xv[e >> 2], e & 3);
            float ratio = xi * frcp(s[pos]);
            float nl    = __builtin_fmaf(oma, lev, lev_a * ratio);
            float ns    = __builtin_fmaf(omb, s[pos], seas_b * (xi * frcp(nl)));
            s[pos] = ns;
            lev = nl;
            levp[0] = nl;  levp += B_;
            nsp[0]  = ns;  nsp  += B_;
        }
    }
}

// ---------------- transpose levT[t][b] -> out_levs[b][t] ----------------
__global__ __launch_bounds__(256) void transposeL_kernel(
    const float* __restrict__ levT, float* __restrict__ out)
{
    __shared__ float tile[32][33];
    int bt = blockIdx.y * 32;
    int bb = blockIdx.x * 32;
    int tx = threadIdx.x, ty = threadIdx.y;          // (32, 8)
    #pragma unroll
    for (int r = 0; r < 32; r += 8)
        tile[ty + r][tx] = levT[(size_t)(bt + ty + r) * B_ + bb + tx];
    __syncthreads();
    #pragma unroll
    for (int r = 0; r < 32; r += 8)
        out[(size_t)(bb + ty + r) * T_ + bt + tx] = tile[tx][ty + r];
}

// ---------------- transpose nsT -> out_seas[b][u], u in [0, 2096) ----------------
// u<25: head = exp(init_seas[idxs[b]][u<24?u:0]); u in [25,2072): row u-25;
// u in [2072,2096): row u-49 (seasonal tail repeat).
__global__ __launch_bounds__(256) void transposeS_kernel(
    const float* __restrict__ nsT, const float* __restrict__ seasonalities,
    const int* __restrict__ idxs, float* __restrict__ out_seas)
{
    __shared__ float tile[32][33];
    int bu = blockIdx.y * 32;
    int bb = blockIdx.x * 32;
    int tx = threadIdx.x, ty = threadIdx.y;
    int id = idxs[bb + tx];
    #pragma unroll
    for (int r = 0; r < 32; r += 8) {
        int u = bu + ty + r;
        if (u < 25) {
            tile[ty + r][tx] = __expf(seasonalities[id * SEAS_ + (u < 24 ? u : 0)]);
        } else if (u < SFW_) {
            int rr = u - 25 - (u >= 2072 ? 24 : 0);
            tile[ty + r][tx] = nsT[(size_t)rr * B_ + bb + tx];
        }
    }
    __syncthreads();
    #pragma unroll
    for (int r = 0; r < 32; r += 8) {
        int u = bu + tx;
        if (u < SFW_)
            out_seas[(size_t)(bb + ty + r) * SFW_ + u] = tile[tx][ty + r];
    }
}

// ---------------- window materialization (243 MB, write-bound) ----------------
__global__ __launch_bounds__(256) void win_kernel(
    const float* __restrict__ x, const float* __restrict__ levs,
    const float* __restrict__ seasF, const float* __restrict__ info_cat,
    vf2* __restrict__ out)
{
    int w  = blockIdx.y;
    int e2 = blockIdx.x * 256 + threadIdx.x;         // 0..15359 == B*15
    int b  = e2 / 15;
    int j  = e2 - b * 15;
    vf2 v;
    if (j < 12) {
        float inv = frcp(levs[b * T_ + w + 23]);
        int t = w + 2 * j;
        float sa = seasF[b * SFW_ + t];
        float sb = seasF[b * SFW_ + t + 1];
        v.x = x[b * T_ + t]     * frcp(sa) * inv;
        v.y = x[b * T_ + t + 1] * frcp(sb) * inv;
    } else {
        int c = 2 * (j - 12);
        v.x = info_cat[b * C_ + c];
        v.y = info_cat[b * C_ + c + 1];
    }
    __builtin_nontemporal_store(v, &out[(size_t)w * 15360 + e2]);
}

// ---------------- msld: mean_b (logL[i+2] - 2 logL[i+1] + logL[i])^2 ----------------
__global__ __launch_bounds__(256) void msld_kernel(
    const float* __restrict__ levT, float* __restrict__ out)
{
    int i = blockIdx.x;                              // 0..2045
    const float* r0 = levT + (size_t)i * B_;
    float ssum = 0.0f;
    #pragma unroll
    for (int r = 0; r < 4; ++r) {
        int b = threadIdx.x + 256 * r;
        float l0 = __logf(r0[b]);
        float l1 = __logf(r0[b + B_]);
        float l2 = __logf(r0[b + 2 * B_]);
        float d  = l2 - 2.0f * l1 + l0;
        ssum = __builtin_fmaf(d, d, ssum);
    }
    #pragma unroll
    for (int off = 32; off > 0; off >>= 1) ssum += __shfl_down(ssum, off);
    __shared__ float partial[4];
    int wid = threadIdx.x >> 6;
    if ((threadIdx.x & 63) == 0) partial[wid] = ssum;
    __syncthreads();
    if (threadIdx.x == 0)
        out[i] = (partial[0] + partial[1] + partial[2] + partial[3]) * (1.0f / 1024.0f);
}

extern "C" void kernel_launch(void* const* d_in, const int* in_sizes, int n_in,
                              void* d_out, int out_size, void* d_ws, size_t ws_size,
                              hipStream_t stream)
{
    const float* train    = (const float*)d_in[0];
    const float* info_cat = (const float*)d_in[3];
    const float* lev_sms  = (const float*)d_in[4];
    const float* seas_sms = (const float*)d_in[5];
    const float* seasonal = (const float*)d_in[6];
    const int*   idxs     = (const int*)d_in[7];

    float* out      = (float*)d_out;
    float* out_ib   = out;                               // W*B*30
    float* out_levs = out + (size_t)W_ * B_ * 30;        // B*2048
    float* out_seas = out_levs + (size_t)B_ * T_;        // B*2096
    float* out_msld = out_seas + (size_t)B_ * SFW_;      // 2046

    float* ws   = (float*)d_ws;
    float* levT = ws;                                    // 2048*1024 floats
    float* nsT  = ws + (size_t)T_ * B_;                  // 2047*1024 floats

    // Exact boundary states live in the head of out_ib: written by phase1, read by
    // phase2, later overwritten by win_kernel (stream-ordered, race-free).
    float* state = out_ib;                               // 16*1024*25 floats (1.6 MB)

    scan_phase1<<<B_, 64, 0, stream>>>(train, lev_sms, seas_sms, seasonal, idxs, state);

    scan_phase2<<<dim3(B_ / 64, NCH_), 64, 0, stream>>>(train, lev_sms, seas_sms,
                                                        seasonal, idxs, state, levT, nsT);

    msld_kernel<<<2046, 256, 0, stream>>>(levT, out_msld);

    dim3 tb(32, 8);
    transposeL_kernel<<<dim3(B_ / 32, T_ / 32), tb, 0, stream>>>(levT, out_levs);
    transposeS_kernel<<<dim3(B_ / 32, (SFW_ + 31) / 32), tb, 0, stream>>>(
        nsT, seasonal, idxs, out_seas);

    dim3 g2(60, W_);
    win_kernel<<<g2, 256, 0, stream>>>(train, out_levs, out_seas, info_cat, (vf2*)out_ib);
}

// Round 16
// 111.854 us; speedup vs baseline: 1.4374x; 1.0787x over previous
//
#include <hip/hip_runtime.h>

#define B_    1024
#define T_    2048
#define SEAS_ 24
#define C_    6
#define W_    1977   // T - OS - IS + 1
#define SFW_  2096   // seas_full width
#define CH_   120    // chunk length (multiple of 24)
#define NCH_  17     // chunks c=0..15: 120 steps; c=16: 127 steps

typedef float vf2 __attribute__((ext_vector_type(2)));

__device__ __forceinline__ float frcp(float x) { return __builtin_amdgcn_rcpf(x); }
__device__ __forceinline__ float getc(const float4& v, int c) {
    return c == 0 ? v.x : c == 1 ? v.y : c == 2 ? v.z : v.w;   // c is compile-time
}

// DPP helpers (VALU pipe, ~4-8 cyc dependent latency — not LDS like ds_bpermute).
// row_shr:N (0x110|N) with bound_ctrl=1: lanes with row-local idx < N read 0.
template <int CTRL>
__device__ __forceinline__ float dpp_z(float v) {              // zero-fill variant
    return __int_as_float(__builtin_amdgcn_update_dpp(
        0, __float_as_int(v), CTRL, 0xf, 0xf, true));
}
// row_bcast15 (0x142), row_mask=0xA: rows 1,3 receive lane15/47 value; rows 0,2 get 0.
__device__ __forceinline__ float dpp_bcast15_z(float v) {
    return __int_as_float(__builtin_amdgcn_update_dpp(
        0, __float_as_int(v), 0x142, 0xa, 0xf, false));
}
__device__ __forceinline__ float readlane_f(float v, int l) {  // l compile-time; SALU
    return __int_as_float(__builtin_amdgcn_readlane(__float_as_int(v), l));
}

// ---------------- Phase 1 block: DPP weighted Kogge-Stone over 24 lanes ----------------
// Lane j owns step-slot j (seasonal slot (j+1)%24).
//   ar_j  = lev_a*(x_j*rcp(s_own))                       (lane-parallel)
//   acc_j = sum_{i<=j} oma^(j-i) ar_i : 4x row_shr in-row scan + row_bcast15 cross-row
//           (lane>=16 adds oma^(ln-15) * prefix@15)
//   lv_j  = fma(oma^(j+1), lev_prev, acc_j)
//   ns_j  = fma(omb, s_own, seas_b*(x_j*rcp(lv_j)))
//   carry: lev = readlane(lv, 23)                        (SALU broadcast)
// Contraction (~0.38/step) keeps reassociation error ~1e-7 relative.
__device__ __forceinline__ void scan_block(
    float xv, float& s_own, float& lev, float lev_a, float seas_b, float omb,
    float p1, float p2, float p4, float p8, float wrow, float myp)
{
    float ar  = lev_a * (xv * frcp(s_own));
    float acc = ar;
    acc = __builtin_fmaf(p1, dpp_z<0x111>(acc), acc);    // row_shr:1
    acc = __builtin_fmaf(p2, dpp_z<0x112>(acc), acc);    // row_shr:2
    acc = __builtin_fmaf(p4, dpp_z<0x114>(acc), acc);    // row_shr:4
    acc = __builtin_fmaf(p8, dpp_z<0x118>(acc), acc);    // row_shr:8
    acc = __builtin_fmaf(wrow, dpp_bcast15_z(acc), acc); // cross-row (lanes 16..23)
    float lv = __builtin_fmaf(myp, lev, acc);            // lev after own step
    float ns = __builtin_fmaf(omb, s_own, seas_b * (xv * frcp(lv)));
    s_own = ns;                                          // lanes >= 24: harmless junk
    lev = readlane_f(lv, 23);                            // block carry (step 23 = slot 0)
}

__global__ __launch_bounds__(64, 1) void scan_phase1(
    const float* __restrict__ x, const float* __restrict__ lev_sms,
    const float* __restrict__ seas_sms, const float* __restrict__ seasonalities,
    const int* __restrict__ idxs, float* __restrict__ state)
{
    int b    = blockIdx.x;                           // one series per wave
    int lane = threadIdx.x;                          // 0..63
    const float* xr = x + (size_t)b * T_;

    int id = idxs[b];
    float lev_a  = 1.0f / (1.0f + __expf(-lev_sms[id]));
    float seas_b = 1.0f / (1.0f + __expf(-seas_sms[id]));
    float oma = 1.0f - lev_a, omb = 1.0f - seas_b;

    // powers of oma; per-lane constants for the scan
    float p1 = oma, p2 = p1 * p1, p4 = p2 * p2, p8 = p4 * p4, p16 = p8 * p8;
    int lp1 = lane + 1;
    float myp = ((lp1 & 1)  ? p1  : 1.0f) * ((lp1 & 2)  ? p2  : 1.0f)
              * ((lp1 & 4)  ? p4  : 1.0f) * ((lp1 & 8)  ? p8  : 1.0f)
              * ((lp1 & 16) ? p16 : 1.0f);           // oma^(lane+1)
    int e = lane - 15;                               // cross-row weight exponent
    float wrow = 0.0f;
    if (e > 0) {
        wrow = ((e & 1) ? p1 : 1.0f) * ((e & 2) ? p2 : 1.0f)
             * ((e & 4) ? p4 : 1.0f) * ((e & 8) ? p8 : 1.0f);   // oma^(lane-15)
    }

    int pos_own = (lane + 1 < 24) ? (lane + 1) : 0;  // lane 23 -> slot 0
    float s_own = 1.0f;
    if (lane < 24) s_own = __expf(seasonalities[id * SEAS_ + pos_own]);

    float s0  = readlane_f(s_own, 23);               // slot 0 initial value
    float lev = xr[0] * frcp(s0);                    // lev0

    float xq0 = xr[1 + lane];                        // blocks 0..4 preloaded
    float xq1 = xr[1 + 24 + lane];
    float xq2 = xr[1 + 48 + lane];
    float xq3 = xr[1 + 72 + lane];
    float xq4 = xr[1 + 96 + lane];

    for (int g = 0; g < 16; ++g) {                   // 16 groups x 5 blocks = t 1..1920
        int base = 1 + (5 * g + 5) * 24 + lane;      // refill target: block 5g+5+i
        scan_block(xq0, s_own, lev, lev_a, seas_b, omb, p1, p2, p4, p8, wrow, myp);
        { int t = base;      xq0 = xr[t > 2047 ? 2047 : t]; }
        scan_block(xq1, s_own, lev, lev_a, seas_b, omb, p1, p2, p4, p8, wrow, myp);
        { int t = base + 24; xq1 = xr[t > 2047 ? 2047 : t]; }
        scan_block(xq2, s_own, lev, lev_a, seas_b, omb, p1, p2, p4, p8, wrow, myp);
        { int t = base + 48; xq2 = xr[t > 2047 ? 2047 : t]; }
        scan_block(xq3, s_own, lev, lev_a, seas_b, omb, p1, p2, p4, p8, wrow, myp);
        { int t = base + 72; xq3 = xr[t > 2047 ? 2047 : t]; }
        scan_block(xq4, s_own, lev, lev_a, seas_b, omb, p1, p2, p4, p8, wrow, myp);
        { int t = base + 96; xq4 = xr[t > 2047 ? 2047 : t]; }
        float* st = state + ((size_t)g * B_ + b) * 25;   // t = 120(g+1) done
        if (lane < 24) st[pos_own] = s_own;
        if (lane == 24) st[24] = lev;
    }
}

// One 24-step block (steps t = 24k+1 .. 24k+24; xv = x[24k .. 24k+27], element e = j+1).
// ILP-exposed sequential arithmetic (exact within each chunk).
template <bool STORE>
__device__ __forceinline__ void es_block24(
    const float4* __restrict__ xv, float* __restrict__ s,
    float lev_a, float oma, float seas_b, float omb, float& lev,
    float* __restrict__ levp, float* __restrict__ nsp)
{
    float ar[24], lv[24];
    #pragma unroll
    for (int j = 0; j < 24; ++j) {
        const int e = j + 1, pos = (j + 1 < 24) ? (j + 1) : 0;
        ar[j] = lev_a * (getc(xv[e >> 2], e & 3) * frcp(s[pos]));
    }
    #pragma unroll
    for (int j = 0; j < 24; ++j) {                   // serial lev chain
        lev = __builtin_fmaf(oma, lev, ar[j]);
        lv[j] = lev;
    }
    #pragma unroll
    for (int j = 0; j < 24; ++j) {                   // independent seasonal updates
        const int e = j + 1, pos = (j + 1 < 24) ? (j + 1) : 0;
        float xi = getc(xv[e >> 2], e & 3);
        float ns = __builtin_fmaf(omb, s[pos], seas_b * (xi * frcp(lv[j])));
        s[pos] = ns;
        if (STORE) {
            levp[(size_t)j * B_] = lv[j];
            nsp[(size_t)j * B_]  = ns;
        }
    }
}

// ---------------- Phase 2: 17 exact chunks in parallel, coalesced heavy stores ---------
// Chunk c: t in [120c+1, min(120(c+1), 2047)] (c=16 adds the 7-step tail to t=2047).
__global__ __launch_bounds__(64, 1) void scan_phase2(
    const float* __restrict__ x, const float* __restrict__ lev_sms,
    const float* __restrict__ seas_sms, const float* __restrict__ seasonalities,
    const int* __restrict__ idxs, const float* __restrict__ state,
    float* __restrict__ levT, float* __restrict__ nsT)
{
    int b = blockIdx.x * 64 + threadIdx.x;
    int c = blockIdx.y;
    const float4* xr4 = (const float4*)(x + (size_t)b * T_);

    int id = idxs[b];
    float lev_a  = 1.0f / (1.0f + __expf(-lev_sms[id]));
    float seas_b = 1.0f / (1.0f + __expf(-seas_sms[id]));
    float oma = 1.0f - lev_a, omb = 1.0f - seas_b;

    float s[SEAS_];
    float lev;
    if (c == 0) {
        #pragma unroll
        for (int j = 0; j < SEAS_; ++j) s[j] = __expf(seasonalities[id * SEAS_ + j]);
        lev = getc(xr4[0], 0) * frcp(s[0]);              // lev0
        levT[b] = lev;                                   // row 0
    } else {
        const float* st = state + ((size_t)(c - 1) * B_ + b) * 25;
        #pragma unroll
        for (int j = 0; j < SEAS_; ++j) s[j] = st[j];
        lev = st[24];
    }

    float4 xv[7], xn[7];
    const float4* base0 = xr4 + 30 * c;                  // t = 120c ..
    #pragma unroll
    for (int q = 0; q < 7; ++q) xv[q] = base0[q];

    float* levp = levT + (size_t)(120 * c + 1) * B_ + b;
    float* nsp  = nsT  + (size_t)(120 * c) * B_ + b;

    #pragma unroll
    for (int kb = 0; kb < 5; ++kb) {                     // 5 blocks of 24 steps
        const float4* nb = xr4 + 30 * c + 6 * (kb + 1);
        if (c == NCH_ - 1 && kb == 4) {                  // next base 510: only 2 in-bounds
            xn[0] = nb[0]; xn[1] = nb[1];
        } else {
            #pragma unroll
            for (int q = 0; q < 7; ++q) xn[q] = nb[q];
        }
        es_block24<true>(xv, s, lev_a, oma, seas_b, omb, lev, levp, nsp);
        levp += (size_t)24 * B_;
        nsp  += (size_t)24 * B_;
        #pragma unroll
        for (int q = 0; q < 7; ++q) xv[q] = xn[q];
    }
    if (c == NCH_ - 1) {                                 // tail t = 2041..2047
        #pragma unroll
        for (int j = 0; j < 7; ++j) {
            const int e = j + 1, pos = j + 1;
            float xi    = getc(xv[e >> 2], e & 3);
            float ratio = xi * frcp(s[pos]);
            float nl    = __builtin_fmaf(oma, lev, lev_a * ratio);
            float ns    = __builtin_fmaf(omb, s[pos], seas_b * (xi * frcp(nl)));
            s[pos] = ns;
            lev = nl;
            levp[0] = nl;  levp += B_;
            nsp[0]  = ns;  nsp  += B_;
        }
    }
}

// ---------------- transpose levT[t][b] -> out_levs[b][t] ----------------
__global__ __launch_bounds__(256) void transposeL_kernel(
    const float* __restrict__ levT, float* __restrict__ out)
{
    __shared__ float tile[32][33];
    int bt = blockIdx.y * 32;
    int bb = blockIdx.x * 32;
    int tx = threadIdx.x, ty = threadIdx.y;          // (32, 8)
    #pragma unroll
    for (int r = 0; r < 32; r += 8)
        tile[ty + r][tx] = levT[(size_t)(bt + ty + r) * B_ + bb + tx];
    __syncthreads();
    #pragma unroll
    for (int r = 0; r < 32; r += 8)
        out[(size_t)(bb + ty + r) * T_ + bt + tx] = tile[tx][ty + r];
}

// ---------------- transpose nsT -> out_seas[b][u], u in [0, 2096) ----------------
// u<25: head = exp(init_seas[idxs[b]][u<24?u:0]); u in [25,2072): row u-25;
// u in [2072,2096): row u-49 (seasonal tail repeat).
__global__ __launch_bounds__(256) void transposeS_kernel(
    const float* __restrict__ nsT, const float* __restrict__ seasonalities,
    const int* __restrict__ idxs, float* __restrict__ out_seas)
{
    __shared__ float tile[32][33];
    int bu = blockIdx.y * 32;
    int bb = blockIdx.x * 32;
    int tx = threadIdx.x, ty = threadIdx.y;
    int id = idxs[bb + tx];
    #pragma unroll
    for (int r = 0; r < 32; r += 8) {
        int u = bu + ty + r;
        if (u < 25) {
            tile[ty + r][tx] = __expf(seasonalities[id * SEAS_ + (u < 24 ? u : 0)]);
        } else if (u < SFW_) {
            int rr = u - 25 - (u >= 2072 ? 24 : 0);
            tile[ty + r][tx] = nsT[(size_t)rr * B_ + bb + tx];
        }
    }
    __syncthreads();
    #pragma unroll
    for (int r = 0; r < 32; r += 8) {
        int u = bu + tx;
        if (u < SFW_)
            out_seas[(size_t)(bb + ty + r) * SFW_ + u] = tile[tx][ty + r];
    }
}

// ---------------- window materialization (243 MB, write-bound) ----------------
__global__ __launch_bounds__(256) void win_kernel(
    const float* __restrict__ x, const float* __restrict__ levs,
    const float* __restrict__ seasF, const float* __restrict__ info_cat,
    vf2* __restrict__ out)
{
    int w  = blockIdx.y;
    int e2 = blockIdx.x * 256 + threadIdx.x;         // 0..15359 == B*15
    int b  = e2 / 15;
    int j  = e2 - b * 15;
    vf2 v;
    if (j < 12) {
        float inv = frcp(levs[b * T_ + w + 23]);
        int t = w + 2 * j;
        float sa = seasF[b * SFW_ + t];
        float sb = seasF[b * SFW_ + t + 1];
        v.x = x[b * T_ + t]     * frcp(sa) * inv;
        v.y = x[b * T_ + t + 1] * frcp(sb) * inv;
    } else {
        int c = 2 * (j - 12);
        v.x = info_cat[b * C_ + c];
        v.y = info_cat[b * C_ + c + 1];
    }
    __builtin_nontemporal_store(v, &out[(size_t)w * 15360 + e2]);
}

// ---------------- msld: mean_b (logL[i+2] - 2 logL[i+1] + logL[i])^2 ----------------
__global__ __launch_bounds__(256) void msld_kernel(
    const float* __restrict__ levT, float* __restrict__ out)
{
    int i = blockIdx.x;                              // 0..2045
    const float* r0 = levT + (size_t)i * B_;
    float ssum = 0.0f;
    #pragma unroll
    for (int r = 0; r < 4; ++r) {
        int b = threadIdx.x + 256 * r;
        float l0 = __logf(r0[b]);
        float l1 = __logf(r0[b + B_]);
        float l2 = __logf(r0[b + 2 * B_]);
        float d  = l2 - 2.0f * l1 + l0;
        ssum = __builtin_fmaf(d, d, ssum);
    }
    #pragma unroll
    for (int off = 32; off > 0; off >>= 1) ssum += __shfl_down(ssum, off);
    __shared__ float partial[4];
    int wid = threadIdx.x >> 6;
    if ((threadIdx.x & 63) == 0) partial[wid] = ssum;
    __syncthreads();
    if (threadIdx.x == 0)
        out[i] = (partial[0] + partial[1] + partial[2] + partial[3]) * (1.0f / 1024.0f);
}

extern "C" void kernel_launch(void* const* d_in, const int* in_sizes, int n_in,
                              void* d_out, int out_size, void* d_ws, size_t ws_size,
                              hipStream_t stream)
{
    const float* train    = (const float*)d_in[0];
    const float* info_cat = (const float*)d_in[3];
    const float* lev_sms  = (const float*)d_in[4];
    const float* seas_sms = (const float*)d_in[5];
    const float* seasonal = (const float*)d_in[6];
    const int*   idxs     = (const int*)d_in[7];

    float* out      = (float*)d_out;
    float* out_ib   = out;                               // W*B*30
    float* out_levs = out + (size_t)W_ * B_ * 30;        // B*2048
    float* out_seas = out_levs + (size_t)B_ * T_;        // B*2096
    float* out_msld = out_seas + (size_t)B_ * SFW_;      // 2046

    float* ws   = (float*)d_ws;
    float* levT = ws;                                    // 2048*1024 floats
    float* nsT  = ws + (size_t)T_ * B_;                  // 2047*1024 floats

    // Exact boundary states live in the head of out_ib: written by phase1, read by
    // phase2, later overwritten by win_kernel (stream-ordered, race-free).
    float* state = out_ib;                               // 16*1024*25 floats (1.6 MB)

    scan_phase1<<<B_, 64, 0, stream>>>(train, lev_sms, seas_sms, seasonal, idxs, state);

    scan_phase2<<<dim3(B_ / 64, NCH_), 64, 0, stream>>>(train, lev_sms, seas_sms,
                                                        seasonal, idxs, state, levT, nsT);

    msld_kernel<<<2046, 256, 0, stream>>>(levT, out_msld);

    dim3 tb(32, 8);
    transposeL_kernel<<<dim3(B_ / 32, T_ / 32), tb, 0, stream>>>(levT, out_levs);
    transposeS_kernel<<<dim3(B_ / 32, (SFW_ + 31) / 32), tb, 0, stream>>>(
        nsT, seasonal, idxs, out_seas);

    dim3 g2(60, W_);
    win_kernel<<<g2, 256, 0, stream>>>(train, out_levs, out_seas, info_cat, (vf2*)out_ib);
}